// Round 4
// baseline (89.793 us; speedup 1.0000x reference)
//
#include <hip/hip_runtime.h>

#define SQ3F 1.7320508075688772f
#define SQ5F 2.2360679774997896f
#define BLOCK 256
#define CHUNK 2048
#define ROUNDS 8        // CHUNK / BLOCK
#define K3_BLOCKS 1024

// m=2 basis matrices (exact transcription of _m2_basis; s = sqrt(3)/2)
__device__ const float M2B[5][3][3] = {
  {{0.f, 0.f, 0.8660254037844386f}, {0.f, 0.f, 0.f}, {0.8660254037844386f, 0.f, 0.f}},
  {{0.f, 0.8660254037844386f, 0.f}, {0.8660254037844386f, 0.f, 0.f}, {0.f, 0.f, 0.f}},
  {{-0.5f, 0.f, 0.f}, {0.f, 1.0f, 0.f}, {0.f, 0.f, -0.5f}},
  {{0.f, 0.f, 0.f}, {0.f, 0.f, 0.8660254037844386f}, {0.f, 0.8660254037844386f, 0.f}},
  {{-0.8660254037844386f, 0.f, 0.f}, {0.f, 0.f, 0.f}, {0.f, 0.f, 0.8660254037844386f}}
};

__device__ __forceinline__ void accum18(float* s, float nx, float ny,
                                        float ex, float ey, float ez) {
  float x2 = ex * ex, y2 = ey * ey, z2 = ez * ez;
  float s1x = SQ3F * ex, s1y = SQ3F * ey, s1z = SQ3F * ez;
  float s20 = SQ5F * SQ3F * ex * ez;
  float s21 = SQ5F * SQ3F * ex * ey;
  float s22 = SQ5F * (y2 - 0.5f * (x2 + z2));
  float s23 = SQ5F * SQ3F * ey * ez;
  float s24 = SQ5F * 0.5f * SQ3F * (z2 - x2);
  s[0] += nx;        s[1] += ny;
  s[2] += nx * s1x;  s[3] += nx * s1y;  s[4] += nx * s1z;
  s[5] += ny * s1x;  s[6] += ny * s1y;  s[7] += ny * s1z;
  s[8]  += nx * s20; s[9]  += nx * s21; s[10] += nx * s22;
  s[11] += nx * s23; s[12] += nx * s24;
  s[13] += ny * s20; s[14] += ny * s21; s[15] += ny * s22;
  s[16] += ny * s23; s[17] += ny * s24;
}

// ---------------- K1: per-chunk mask counts (float4 pass) + init ----------
__global__ void __launch_bounds__(BLOCK)
count_kernel(const float4* __restrict__ x4, int N, int* __restrict__ counts,
             float* __restrict__ accum, int* __restrict__ done) {
  const int b = blockIdx.x, t = threadIdx.x;
  if (b == 0) {
    if (t < 18) accum[t] = 0.f;
    if (t == 18) *done = 0;
  }
  const int base4 = b * (CHUNK / 2);   // float4 = 2 float2 elements
  int cf = 0, ct = 0;
#pragma unroll
  for (int r = 0; r < ROUNDS / 2; ++r) {
    int i4 = base4 + r * BLOCK + t;
    if (2 * i4 < N) {                  // N even -> both elements valid together
      float4 v = x4[i4];
      cf += (v.x > 0.5f) + (v.z > 0.5f);
      ct += (v.y > 0.5f) + (v.w > 0.5f);
    }
  }
  for (int o = 32; o; o >>= 1) { cf += __shfl_down(cf, o); ct += __shfl_down(ct, o); }
  __shared__ int sF[4], sT[4];
  const int lane = t & 63, wave = t >> 6;
  if (lane == 0) { sF[wave] = cf; sT[wave] = ct; }
  __syncthreads();
  if (t == 0) {
    counts[2 * b]     = sF[0] + sF[1] + sF[2] + sF[3];
    counts[2 * b + 1] = sT[0] + sT[1] + sT[2] + sT[3];
  }
}

// ---------------- K2: self-scan + stable compaction, direct writes --------
__global__ void __launch_bounds__(BLOCK)
scatter_kernel(const float2* __restrict__ x, int N, int E, int nchunks,
               const int* __restrict__ counts,
               int* __restrict__ from_idx, int* __restrict__ to_idx,
               int* __restrict__ header) {
  const int b = blockIdx.x, t = threadIdx.x;
  const int lane = t & 63, wave = t >> 6;

  // self-scan: exclusive prefix for this block + grand totals
  int preF = 0, preT = 0, totF = 0, totT = 0;
  for (int k = t; k < nchunks; k += BLOCK) {
    int a = counts[2 * k], c = counts[2 * k + 1];
    totF += a; totT += c;
    if (k < b) { preF += a; preT += c; }
  }
  for (int o = 32; o; o >>= 1) {
    preF += __shfl_down(preF, o); preT += __shfl_down(preT, o);
    totF += __shfl_down(totF, o); totT += __shfl_down(totT, o);
  }
  __shared__ int red[4][4];
  if (lane == 0) { red[wave][0] = preF; red[wave][1] = preT;
                   red[wave][2] = totF; red[wave][3] = totT; }
  __syncthreads();
  int baseF = red[0][0] + red[1][0] + red[2][0] + red[3][0];
  int baseT = red[0][1] + red[1][1] + red[2][1] + red[3][1];
  if (b == 0 && t == 0) {
    header[0] = red[0][2] + red[1][2] + red[2][2] + red[3][2];
    header[1] = red[0][3] + red[1][3] + red[2][3] + red[3][3];
  }

  // ballot compaction, double-buffered wave counts (1 sync per round)
  __shared__ int wc[2][4][2];
  const int chunkBase = b * CHUNK;
  for (int r = 0; r < ROUNDS; ++r) {
    const int i = chunkBase + r * BLOCK + t;
    bool mf = false, mt = false;
    if (i < N) { float2 v = x[i]; mf = v.x > 0.5f; mt = v.y > 0.5f; }
    unsigned long long bf = __ballot(mf);
    unsigned long long bt = __ballot(mt);
    const int p = r & 1;
    if (lane == 0) { wc[p][wave][0] = __popcll(bf); wc[p][wave][1] = __popcll(bt); }
    __syncthreads();
    int woF = 0, woT = 0, rtF = 0, rtT = 0;
    for (int w = 0; w < 4; ++w) {
      int a = wc[p][w][0], c = wc[p][w][1];
      if (w < wave) { woF += a; woT += c; }
      rtF += a; rtT += c;
    }
    unsigned long long lm = (1ull << lane) - 1ull;
    if (mf) { int rk = baseF + woF + (int)__popcll(bf & lm); if (rk < E) from_idx[rk] = i; }
    if (mt) { int rk = baseT + woT + (int)__popcll(bt & lm); if (rk < E) to_idx[rk] = i; }
    baseF += rtF; baseT += rtT;
  }
}

// ---------------- K3: edge reduction + fused finalize (last block) --------
__global__ void __launch_bounds__(BLOCK)
reduce_finalize_kernel(const float2* __restrict__ x, const float* __restrict__ pos,
                       const int* __restrict__ from_idx, const int* __restrict__ to_idx,
                       const int* __restrict__ header, int E,
                       float* __restrict__ accum, int* __restrict__ done,
                       const float* __restrict__ w0, const float* __restrict__ w1,
                       const float* __restrict__ w2, const float* __restrict__ w_0e2e,
                       const float* __restrict__ w_2e0e, const float* __restrict__ w_1o1o,
                       const float* __restrict__ w_2e2e, float* __restrict__ out) {
  const int t = threadIdx.x;
  const int lane = t & 63, wave = t >> 6;
  int cF = header[0], cT = header[1];
  if (cF > E) cF = E;
  if (cT > E) cT = E;

  float s[18];
#pragma unroll
  for (int j = 0; j < 18; ++j) s[j] = 0.f;
  const int stride = gridDim.x * BLOCK;
  for (int k = blockIdx.x * BLOCK + t; k < E; k += stride) {
    int f  = (k < cF) ? from_idx[k] : 0;   // nonzero pad fill_value = 0
    int tt = (k < cT) ? to_idx[k]   : 0;
    float2 nf = x[tt];
    float ex = pos[3 * tt]     - pos[3 * f];
    float ey = pos[3 * tt + 1] - pos[3 * f + 1];
    float ez = pos[3 * tt + 2] - pos[3 * f + 2];
    accum18(s, nf.x, nf.y, ex, ey, ez);
  }
#pragma unroll
  for (int j = 0; j < 18; ++j)
    for (int o = 32; o; o >>= 1) s[j] += __shfl_down(s[j], o);
  __shared__ float ls[4][18];
  if (lane == 0) {
#pragma unroll
    for (int j = 0; j < 18; ++j) ls[wave][j] = s[j];
  }
  __syncthreads();
  if (t < 18) atomicAdd(&accum[t], ls[0][t] + ls[1][t] + ls[2][t] + ls[3][t]);
  __threadfence();
  __syncthreads();

  __shared__ int lastFlag;
  if (t == 0) lastFlag = (atomicAdd(done, 1) == (int)gridDim.x - 1);
  __syncthreads();
  if (!lastFlag) return;
  __threadfence();

  // ---------- finalize (whole last block) ----------
  __shared__ float g0[64], g1[24][3], g2[16][5];
  __shared__ float a16[16], c16[16], T1[24][3], T2[16][5];
  __shared__ float A1[3][3], A2[5][5];
  __shared__ float W112s[45], W222s[125];
  __shared__ float rn112, rn222, accS[18];

  if (t < 18) accS[t] = atomicAdd(&accum[t], 0.0f);  // coherent read
  if (t >= 64 && t < 109) W112s[t - 64] = 0.f;
  __syncthreads();

  const float inv = 0.28867513459481287f;  // 1/sqrt(12)
  if (t < 64) {
    g0[t] = inv * (accS[0] * w0[t] + accS[1] * w0[64 + t]);
  } else if (t < 136) {
    int i2 = t - 64, w = i2 / 3, j = i2 % 3;
    g1[w][j] = inv * (accS[2 + j] * w1[w] + accS[5 + j] * w1[24 + w]);
  } else if (t < 216) {
    int i2 = t - 136, w = i2 / 5, j = i2 % 5;
    g2[w][j] = inv * (accS[8 + j] * w2[w] + accS[13 + j] * w2[16 + w]);
  } else if (t < 241) {  // build W222 (25 threads)
    int idx = t - 216, i = idx / 5, j = idx % 5;
    float P[3][3];
    for (int a = 0; a < 3; ++a)
      for (int bb = 0; bb < 3; ++bb) {
        float sacc = 0.f;
        for (int cc = 0; cc < 3; ++cc)
          sacc += M2B[i][a][cc] * M2B[j][cc][bb] + M2B[j][a][cc] * M2B[i][cc][bb];
        P[a][bb] = 0.5f * sacc;
      }
    float tr3 = (P[0][0] + P[1][1] + P[2][2]) * (1.0f / 3.0f);
    P[0][0] -= tr3; P[1][1] -= tr3; P[2][2] -= tr3;
    for (int k = 0; k < 5; ++k) {
      float sacc = 0.f;
      for (int a = 0; a < 3; ++a)
        for (int bb = 0; bb < 3; ++bb) sacc += P[a][bb] * M2B[k][bb][a];
      W222s[(i * 5 + j) * 5 + k] = sacc * (1.0f / 1.5f);
    }
  }
  if (t == 0) {  // W112 nonzeros
    const float sq = 0.8660254037844386f;
    W112s[(0 * 3 + 2) * 5 + 0] = sq;  W112s[(2 * 3 + 0) * 5 + 0] = sq;
    W112s[(0 * 3 + 1) * 5 + 1] = sq;  W112s[(1 * 3 + 0) * 5 + 1] = sq;
    W112s[(1 * 3 + 1) * 5 + 2] = 1.0f;
    W112s[(0 * 3 + 0) * 5 + 2] = -0.5f;
    W112s[(2 * 3 + 2) * 5 + 2] = -0.5f;
    W112s[(1 * 3 + 2) * 5 + 3] = sq;  W112s[(2 * 3 + 1) * 5 + 3] = sq;
    W112s[(2 * 3 + 2) * 5 + 4] = sq;
    W112s[(0 * 3 + 0) * 5 + 4] = -sq;
  }
  __syncthreads();
  if (t == 0) { float ss = 0.f; for (int i = 0; i < 45; ++i)  ss += W112s[i] * W112s[i]; rn112 = rsqrtf(ss); }
  if (t == 1) { float ss = 0.f; for (int i = 0; i < 125; ++i) ss += W222s[i] * W222s[i]; rn222 = rsqrtf(ss); }
  __syncthreads();
  if (t < 45) W112s[t] *= rn112;
  else if (t < 170) W222s[t - 45] *= rn222;
  __syncthreads();

  if (t < 16) {
    float ssum = 0.f; for (int u = 0; u < 64; ++u) ssum += w_0e2e[u * 16 + t] * g0[u];
    a16[t] = ssum;
  } else if (t < 32) {
    int u = t - 16; float ssum = 0.f;
    for (int v = 0; v < 64; ++v) ssum += w_2e0e[u * 64 + v] * g0[v];
    c16[u] = ssum;
  } else if (t < 104) {
    int i2 = t - 32, u = i2 / 3, j = i2 % 3; float ssum = 0.f;
    for (int v = 0; v < 24; ++v) ssum += w_1o1o[u * 24 + v] * g1[v][j];
    T1[u][j] = ssum;
  } else if (t < 184) {
    int i2 = t - 104, u = i2 / 5, j = i2 % 5; float ssum = 0.f;
    for (int v = 0; v < 16; ++v) ssum += w_2e2e[u * 16 + v] * g2[v][j];
    T2[u][j] = ssum;
  }
  __syncthreads();
  if (t < 9) {
    int i = t / 3, j = t % 3; float ssum = 0.f;
    for (int u = 0; u < 24; ++u) ssum += g1[u][i] * T1[u][j];
    A1[i][j] = ssum;
  } else if (t < 34) {
    int i2 = t - 9, i = i2 / 5, j = i2 % 5; float ssum = 0.f;
    for (int u = 0; u < 16; ++u) ssum += g2[u][i] * T2[u][j];
    A2[i][j] = ssum;
  }
  __syncthreads();
  if (t < 5) {
    const float inv_s5 = 0.4472135954999579f;
    const float c = sqrtf(5.0f / 5248.0f);
    float s12 = 0.f;
    for (int v = 0; v < 16; ++v) s12 += (a16[v] + c16[v]) * g2[v][t];
    float s3 = 0.f;
    for (int i = 0; i < 3; ++i)
      for (int j = 0; j < 3; ++j) s3 += A1[i][j] * W112s[(i * 3 + j) * 5 + t];
    float s4 = 0.f;
    for (int i = 0; i < 5; ++i)
      for (int j = 0; j < 5; ++j) s4 += A2[i][j] * W222s[(i * 5 + j) * 5 + t];
    out[t] = c * (inv_s5 * s12 + s3 + s4);
  }
}

extern "C" void kernel_launch(void* const* d_in, const int* in_sizes, int n_in,
                              void* d_out, int out_size, void* d_ws, size_t ws_size,
                              hipStream_t stream) {
  const float2* x      = (const float2*)d_in[0];
  const float*  pos    = (const float*)d_in[1];
  const float*  tp1_w0 = (const float*)d_in[2];
  const float*  tp1_w1 = (const float*)d_in[3];
  const float*  tp1_w2 = (const float*)d_in[4];
  const float*  w_0e2e = (const float*)d_in[5];
  const float*  w_2e0e = (const float*)d_in[6];
  const float*  w_1o1o = (const float*)d_in[7];
  const float*  w_2e2e = (const float*)d_in[8];
  float* outp = (float*)d_out;

  const int N = in_sizes[0] / 2;
  const int E = N / 2;
  const int nchunks = (N + CHUNK - 1) / CHUNK;   // 977 for N=2e6

  // ws layout: [accum 18f][done][header 2i] pad->128B | counts 16KB | from_idx E | to_idx E
  char* ws = (char*)d_ws;
  float* accum  = (float*)ws;
  int*   done   = (int*)(ws + 72);
  int*   header = (int*)(ws + 76);
  int*   counts = (int*)(ws + 128);
  int*   from_idx = (int*)(ws + 128 + 16384);
  int*   to_idx   = from_idx + E;

  count_kernel<<<nchunks, BLOCK, 0, stream>>>((const float4*)x, N, counts, accum, done);
  scatter_kernel<<<nchunks, BLOCK, 0, stream>>>(x, N, E, nchunks, counts,
                                                from_idx, to_idx, header);
  reduce_finalize_kernel<<<K3_BLOCKS, BLOCK, 0, stream>>>(x, pos, from_idx, to_idx,
                                                          header, E, accum, done,
                                                          tp1_w0, tp1_w1, tp1_w2,
                                                          w_0e2e, w_2e0e, w_1o1o, w_2e2e,
                                                          outp);
}

// Round 5
// 37.334 us; speedup vs baseline: 2.4051x; 2.4051x over previous
//
#include <hip/hip_runtime.h>

#define SQ3F 1.7320508075688772f
#define SQ5F 2.2360679774997896f
#define BLOCK 256
#define CHUNK 2048
#define ROUNDS 8        // CHUNK / BLOCK
#define K3_BLOCKS 1024

// m=2 basis matrices (exact transcription of _m2_basis; s = sqrt(3)/2)
__device__ const float M2B[5][3][3] = {
  {{0.f, 0.f, 0.8660254037844386f}, {0.f, 0.f, 0.f}, {0.8660254037844386f, 0.f, 0.f}},
  {{0.f, 0.8660254037844386f, 0.f}, {0.8660254037844386f, 0.f, 0.f}, {0.f, 0.f, 0.f}},
  {{-0.5f, 0.f, 0.f}, {0.f, 1.0f, 0.f}, {0.f, 0.f, -0.5f}},
  {{0.f, 0.f, 0.f}, {0.f, 0.f, 0.8660254037844386f}, {0.f, 0.8660254037844386f, 0.f}},
  {{-0.8660254037844386f, 0.f, 0.f}, {0.f, 0.f, 0.f}, {0.f, 0.f, 0.8660254037844386f}}
};

__device__ __forceinline__ void accum18(float* s, float nx, float ny,
                                        float ex, float ey, float ez) {
  float x2 = ex * ex, y2 = ey * ey, z2 = ez * ez;
  float s1x = SQ3F * ex, s1y = SQ3F * ey, s1z = SQ3F * ez;
  float s20 = SQ5F * SQ3F * ex * ez;
  float s21 = SQ5F * SQ3F * ex * ey;
  float s22 = SQ5F * (y2 - 0.5f * (x2 + z2));
  float s23 = SQ5F * SQ3F * ey * ez;
  float s24 = SQ5F * 0.5f * SQ3F * (z2 - x2);
  s[0] += nx;        s[1] += ny;
  s[2] += nx * s1x;  s[3] += nx * s1y;  s[4] += nx * s1z;
  s[5] += ny * s1x;  s[6] += ny * s1y;  s[7] += ny * s1z;
  s[8]  += nx * s20; s[9]  += nx * s21; s[10] += nx * s22;
  s[11] += nx * s23; s[12] += nx * s24;
  s[13] += ny * s20; s[14] += ny * s21; s[15] += ny * s22;
  s[16] += ny * s23; s[17] += ny * s24;
}

// ---------------- K1: per-chunk mask counts (float4 pass) ----------------
__global__ void __launch_bounds__(BLOCK)
count_kernel(const float4* __restrict__ x4, int N, int* __restrict__ counts) {
  const int b = blockIdx.x, t = threadIdx.x;
  const int base4 = b * (CHUNK / 2);   // float4 = 2 float2 elements
  int cf = 0, ct = 0;
#pragma unroll
  for (int r = 0; r < ROUNDS / 2; ++r) {
    int i4 = base4 + r * BLOCK + t;
    if (2 * i4 < N) {                  // N even -> both elements valid together
      float4 v = x4[i4];
      cf += (v.x > 0.5f) + (v.z > 0.5f);
      ct += (v.y > 0.5f) + (v.w > 0.5f);
    }
  }
  for (int o = 32; o; o >>= 1) { cf += __shfl_down(cf, o); ct += __shfl_down(ct, o); }
  __shared__ int sF[4], sT[4];
  const int lane = t & 63, wave = t >> 6;
  if (lane == 0) { sF[wave] = cf; sT[wave] = ct; }
  __syncthreads();
  if (t == 0) {
    counts[2 * b]     = sF[0] + sF[1] + sF[2] + sF[3];
    counts[2 * b + 1] = sT[0] + sT[1] + sT[2] + sT[3];
  }
}

// ---------------- K2: self-scan + stable compaction + tail zero-fill ------
__global__ void __launch_bounds__(BLOCK)
scatter_kernel(const float2* __restrict__ x, int N, int E, int nchunks,
               const int* __restrict__ counts,
               int* __restrict__ from_idx, int* __restrict__ to_idx) {
  const int b = blockIdx.x, t = threadIdx.x;
  const int lane = t & 63, wave = t >> 6;

  // self-scan: exclusive prefix for this block + grand totals
  int preF = 0, preT = 0, totF = 0, totT = 0;
  for (int k = t; k < nchunks; k += BLOCK) {
    int a = counts[2 * k], c = counts[2 * k + 1];
    totF += a; totT += c;
    if (k < b) { preF += a; preT += c; }
  }
  for (int o = 32; o; o >>= 1) {
    preF += __shfl_down(preF, o); preT += __shfl_down(preT, o);
    totF += __shfl_down(totF, o); totT += __shfl_down(totT, o);
  }
  __shared__ int red[4][4];
  if (lane == 0) { red[wave][0] = preF; red[wave][1] = preT;
                   red[wave][2] = totF; red[wave][3] = totT; }
  __syncthreads();
  int baseF = red[0][0] + red[1][0] + red[2][0] + red[3][0];
  int baseT = red[0][1] + red[1][1] + red[2][1] + red[3][1];
  const int cFall = red[0][2] + red[1][2] + red[2][2] + red[3][2];
  const int cTall = red[0][3] + red[1][3] + red[2][3] + red[3][3];

  // ballot compaction, double-buffered wave counts (1 sync per round)
  __shared__ int wc[2][4][2];
  const int chunkBase = b * CHUNK;
  for (int r = 0; r < ROUNDS; ++r) {
    const int i = chunkBase + r * BLOCK + t;
    bool mf = false, mt = false;
    if (i < N) { float2 v = x[i]; mf = v.x > 0.5f; mt = v.y > 0.5f; }
    unsigned long long bf = __ballot(mf);
    unsigned long long bt = __ballot(mt);
    const int p = r & 1;
    if (lane == 0) { wc[p][wave][0] = __popcll(bf); wc[p][wave][1] = __popcll(bt); }
    __syncthreads();
    int woF = 0, woT = 0, rtF = 0, rtT = 0;
    for (int w = 0; w < 4; ++w) {
      int a = wc[p][w][0], c = wc[p][w][1];
      if (w < wave) { woF += a; woT += c; }
      rtF += a; rtT += c;
    }
    unsigned long long lm = (1ull << lane) - 1ull;
    if (mf) { int rk = baseF + woF + (int)__popcll(bf & lm); if (rk < E) from_idx[rk] = i; }
    if (mt) { int rk = baseT + woT + (int)__popcll(bt & lm); if (rk < E) to_idx[rk] = i; }
    baseF += rtF; baseT += rtT;
  }

  // nonzero() pad semantics: fill_value = 0 beyond grand totals
  const int gstride = gridDim.x * BLOCK;
  for (int rk = cFall + b * BLOCK + t; rk < E; rk += gstride) from_idx[rk] = 0;
  for (int rk = cTall + b * BLOCK + t; rk < E; rk += gstride) to_idx[rk] = 0;
}

// ---------------- K3: edge reduction -> per-block partials (plain stores) --
__global__ void __launch_bounds__(BLOCK)
edge_reduce_kernel(const float2* __restrict__ x, const float* __restrict__ pos,
                   const int* __restrict__ from_idx, const int* __restrict__ to_idx,
                   int E, float* __restrict__ partials) {
  const int t = threadIdx.x;
  const int lane = t & 63, wave = t >> 6;
  float s[18];
#pragma unroll
  for (int j = 0; j < 18; ++j) s[j] = 0.f;

  const int Epairs = E >> 1;
  const int stride = gridDim.x * BLOCK;
  const int2* f2 = (const int2*)from_idx;
  const int2* t2 = (const int2*)to_idx;
  for (int p = blockIdx.x * BLOCK + t; p < Epairs; p += stride) {
    int2 fp = f2[p];
    int2 tp = t2[p];
    float2 nf0 = x[tp.x];
    float2 nf1 = x[tp.y];
    float ax0 = pos[3 * tp.x]     - pos[3 * fp.x];
    float ay0 = pos[3 * tp.x + 1] - pos[3 * fp.x + 1];
    float az0 = pos[3 * tp.x + 2] - pos[3 * fp.x + 2];
    float ax1 = pos[3 * tp.y]     - pos[3 * fp.y];
    float ay1 = pos[3 * tp.y + 1] - pos[3 * fp.y + 1];
    float az1 = pos[3 * tp.y + 2] - pos[3 * fp.y + 2];
    accum18(s, nf0.x, nf0.y, ax0, ay0, az0);
    accum18(s, nf1.x, nf1.y, ax1, ay1, az1);
  }
  if ((E & 1) && blockIdx.x == 0 && t == 0) {
    int f = from_idx[E - 1], tt = to_idx[E - 1];
    float2 nf = x[tt];
    accum18(s, nf.x, nf.y, pos[3 * tt] - pos[3 * f],
            pos[3 * tt + 1] - pos[3 * f + 1], pos[3 * tt + 2] - pos[3 * f + 2]);
  }

#pragma unroll
  for (int j = 0; j < 18; ++j)
    for (int o = 32; o; o >>= 1) s[j] += __shfl_down(s[j], o);
  __shared__ float ls[4][18];
  if (lane == 0) {
#pragma unroll
    for (int j = 0; j < 18; ++j) ls[wave][j] = s[j];
  }
  __syncthreads();
  if (t < 18)
    partials[blockIdx.x * 18 + t] = ls[0][t] + ls[1][t] + ls[2][t] + ls[3][t];
}

// ---------------- K4: reduce partials + finalize (1 block) ----------------
__global__ void __launch_bounds__(BLOCK)
finalize_kernel(const float* __restrict__ partials, int nparts,
                const float* __restrict__ w0, const float* __restrict__ w1,
                const float* __restrict__ w2, const float* __restrict__ w_0e2e,
                const float* __restrict__ w_2e0e, const float* __restrict__ w_1o1o,
                const float* __restrict__ w_2e2e, float* __restrict__ out) {
  const int t = threadIdx.x;
  const int lane = t & 63, wave = t >> 6;
  float s[18];
#pragma unroll
  for (int j = 0; j < 18; ++j) s[j] = 0.f;
  for (int b = t; b < nparts; b += BLOCK) {
#pragma unroll
    for (int j = 0; j < 18; ++j) s[j] += partials[b * 18 + j];
  }
#pragma unroll
  for (int j = 0; j < 18; ++j)
    for (int o = 32; o; o >>= 1) s[j] += __shfl_down(s[j], o);
  __shared__ float ls[4][18];
  __shared__ float accS[18];
  if (lane == 0) {
#pragma unroll
    for (int j = 0; j < 18; ++j) ls[wave][j] = s[j];
  }
  __syncthreads();
  if (t < 18) accS[t] = ls[0][t] + ls[1][t] + ls[2][t] + ls[3][t];

  __shared__ float g0[64], g1[24][3], g2[16][5];
  __shared__ float a16[16], c16[16], T1[24][3], T2[16][5];
  __shared__ float A1[3][3], A2[5][5];
  __shared__ float W112s[45], W222s[125];
  __shared__ float rn112, rn222;
  if (t >= 64 && t < 109) W112s[t - 64] = 0.f;
  __syncthreads();

  const float inv = 0.28867513459481287f;  // 1/sqrt(12)
  if (t < 64) {
    g0[t] = inv * (accS[0] * w0[t] + accS[1] * w0[64 + t]);
  } else if (t < 136) {
    int i2 = t - 64, w = i2 / 3, j = i2 % 3;
    g1[w][j] = inv * (accS[2 + j] * w1[w] + accS[5 + j] * w1[24 + w]);
  } else if (t < 216) {
    int i2 = t - 136, w = i2 / 5, j = i2 % 5;
    g2[w][j] = inv * (accS[8 + j] * w2[w] + accS[13 + j] * w2[16 + w]);
  } else if (t < 241) {  // build W222 (25 threads)
    int idx = t - 216, i = idx / 5, j = idx % 5;
    float P[3][3];
    for (int a = 0; a < 3; ++a)
      for (int bb = 0; bb < 3; ++bb) {
        float sacc = 0.f;
        for (int cc = 0; cc < 3; ++cc)
          sacc += M2B[i][a][cc] * M2B[j][cc][bb] + M2B[j][a][cc] * M2B[i][cc][bb];
        P[a][bb] = 0.5f * sacc;
      }
    float tr3 = (P[0][0] + P[1][1] + P[2][2]) * (1.0f / 3.0f);
    P[0][0] -= tr3; P[1][1] -= tr3; P[2][2] -= tr3;
    for (int k = 0; k < 5; ++k) {
      float sacc = 0.f;
      for (int a = 0; a < 3; ++a)
        for (int bb = 0; bb < 3; ++bb) sacc += P[a][bb] * M2B[k][bb][a];
      W222s[(i * 5 + j) * 5 + k] = sacc * (1.0f / 1.5f);
    }
  }
  if (t == 0) {  // W112 nonzeros
    const float sq = 0.8660254037844386f;
    W112s[(0 * 3 + 2) * 5 + 0] = sq;  W112s[(2 * 3 + 0) * 5 + 0] = sq;
    W112s[(0 * 3 + 1) * 5 + 1] = sq;  W112s[(1 * 3 + 0) * 5 + 1] = sq;
    W112s[(1 * 3 + 1) * 5 + 2] = 1.0f;
    W112s[(0 * 3 + 0) * 5 + 2] = -0.5f;
    W112s[(2 * 3 + 2) * 5 + 2] = -0.5f;
    W112s[(1 * 3 + 2) * 5 + 3] = sq;  W112s[(2 * 3 + 1) * 5 + 3] = sq;
    W112s[(2 * 3 + 2) * 5 + 4] = sq;
    W112s[(0 * 3 + 0) * 5 + 4] = -sq;
  }
  __syncthreads();
  if (t == 0) { float ss = 0.f; for (int i = 0; i < 45; ++i)  ss += W112s[i] * W112s[i]; rn112 = rsqrtf(ss); }
  if (t == 1) { float ss = 0.f; for (int i = 0; i < 125; ++i) ss += W222s[i] * W222s[i]; rn222 = rsqrtf(ss); }
  __syncthreads();
  if (t < 45) W112s[t] *= rn112;
  else if (t < 170) W222s[t - 45] *= rn222;
  __syncthreads();

  if (t < 16) {
    float ssum = 0.f; for (int u = 0; u < 64; ++u) ssum += w_0e2e[u * 16 + t] * g0[u];
    a16[t] = ssum;
  } else if (t < 32) {
    int u = t - 16; float ssum = 0.f;
    for (int v = 0; v < 64; ++v) ssum += w_2e0e[u * 64 + v] * g0[v];
    c16[u] = ssum;
  } else if (t < 104) {
    int i2 = t - 32, u = i2 / 3, j = i2 % 3; float ssum = 0.f;
    for (int v = 0; v < 24; ++v) ssum += w_1o1o[u * 24 + v] * g1[v][j];
    T1[u][j] = ssum;
  } else if (t < 184) {
    int i2 = t - 104, u = i2 / 5, j = i2 % 5; float ssum = 0.f;
    for (int v = 0; v < 16; ++v) ssum += w_2e2e[u * 16 + v] * g2[v][j];
    T2[u][j] = ssum;
  }
  __syncthreads();
  if (t < 9) {
    int i = t / 3, j = t % 3; float ssum = 0.f;
    for (int u = 0; u < 24; ++u) ssum += g1[u][i] * T1[u][j];
    A1[i][j] = ssum;
  } else if (t < 34) {
    int i2 = t - 9, i = i2 / 5, j = i2 % 5; float ssum = 0.f;
    for (int u = 0; u < 16; ++u) ssum += g2[u][i] * T2[u][j];
    A2[i][j] = ssum;
  }
  __syncthreads();
  if (t < 5) {
    const float inv_s5 = 0.4472135954999579f;
    const float c = sqrtf(5.0f / 5248.0f);
    float s12 = 0.f;
    for (int v = 0; v < 16; ++v) s12 += (a16[v] + c16[v]) * g2[v][t];
    float s3 = 0.f;
    for (int i = 0; i < 3; ++i)
      for (int j = 0; j < 3; ++j) s3 += A1[i][j] * W112s[(i * 3 + j) * 5 + t];
    float s4 = 0.f;
    for (int i = 0; i < 5; ++i)
      for (int j = 0; j < 5; ++j) s4 += A2[i][j] * W222s[(i * 5 + j) * 5 + t];
    out[t] = c * (inv_s5 * s12 + s3 + s4);
  }
}

extern "C" void kernel_launch(void* const* d_in, const int* in_sizes, int n_in,
                              void* d_out, int out_size, void* d_ws, size_t ws_size,
                              hipStream_t stream) {
  const float2* x      = (const float2*)d_in[0];
  const float*  pos    = (const float*)d_in[1];
  const float*  tp1_w0 = (const float*)d_in[2];
  const float*  tp1_w1 = (const float*)d_in[3];
  const float*  tp1_w2 = (const float*)d_in[4];
  const float*  w_0e2e = (const float*)d_in[5];
  const float*  w_2e0e = (const float*)d_in[6];
  const float*  w_1o1o = (const float*)d_in[7];
  const float*  w_2e2e = (const float*)d_in[8];
  float* outp = (float*)d_out;

  const int N = in_sizes[0] / 2;
  const int E = N / 2;
  const int nchunks = (N + CHUNK - 1) / CHUNK;   // 977 for N=2e6

  // ws layout: counts 16KB | partials 80KB | from_idx E | to_idx E
  char* ws = (char*)d_ws;
  int*   counts   = (int*)ws;
  float* partials = (float*)(ws + 16384);
  int*   from_idx = (int*)(ws + 16384 + 81920);
  int*   to_idx   = from_idx + E;

  count_kernel<<<nchunks, BLOCK, 0, stream>>>((const float4*)x, N, counts);
  scatter_kernel<<<nchunks, BLOCK, 0, stream>>>(x, N, E, nchunks, counts,
                                                from_idx, to_idx);
  edge_reduce_kernel<<<K3_BLOCKS, BLOCK, 0, stream>>>(x, pos, from_idx, to_idx,
                                                      E, partials);
  finalize_kernel<<<1, BLOCK, 0, stream>>>(partials, K3_BLOCKS,
                                           tp1_w0, tp1_w1, tp1_w2,
                                           w_0e2e, w_2e0e, w_1o1o, w_2e2e, outp);
}